// Round 1
// baseline (7656.261 us; speedup 1.0000x reference)
//
#include <hip/hip_runtime.h>
#include <math.h>

// ---------------- problem constants ----------------
#define N_NODES 50000
#define N_EDGES 800000
#define NF 92           // node features
#define EF 41           // edge features
#define GF 180          // global attr
#define Z  225          // 2*NF + EF
#define NC 184          // 2*NF (fused Wf|Ws output columns)

// edge kernel tiling
#define BE 32           // edges per block
#define KC 25           // K-chunk staged in LDS (225 = 9*25)
#define NKT 9
#define EBLOCK 192      // threads (3 waves); 184 active in compute (4 eg x 46 cg)

__device__ __forceinline__ float sigmoidf_(float x) { return 1.0f / (1.0f + expf(-x)); }
__device__ __forceinline__ float softplusf_(float x) { return fmaxf(x, 0.0f) + log1pf(expf(-fabsf(x))); }
__device__ __forceinline__ float siluf_(float x) { return x * sigmoidf_(x); }

// ---------------- fused CGConv edge kernel ----------------
// For 32 edges: z = [h[dst] | h[src] | edge_attr] (225), compute
// f = z@Wf, s = z@Ws (92 cols each), msg = sigmoid(f+bf)*softplus(s+bs),
// atomicAdd into agg[dst].
__global__ __launch_bounds__(EBLOCK) void edge_kernel(
    const float* __restrict__ h, const int* __restrict__ ei,
    const float* __restrict__ ea,
    const float* __restrict__ Wf, const float* __restrict__ bf,
    const float* __restrict__ Ws, const float* __restrict__ bs,
    float* __restrict__ agg)
{
    __shared__ float zT[Z][36];      // z transposed: zT[k][edge], pad 36 for 16B-aligned rows
    __shared__ float wb[KC][NC];     // staged weight chunk (fused Wf|Ws columns)
    __shared__ int ssrc[BE], sdst[BE];

    const int tid = threadIdx.x;
    const long eb = (long)blockIdx.x * BE;

    if (tid < BE) {
        ssrc[tid] = ei[eb + tid];            // edge_index[0] = src
        sdst[tid] = ei[N_EDGES + eb + tid];  // edge_index[1] = dst
    }
    __syncthreads();

    // gather z into LDS (transposed)
    for (int i = tid; i < BE * Z; i += EBLOCK) {
        int e = i / Z, k = i - e * Z;
        float v;
        if (k < NF)            v = h[(long)sdst[e] * NF + k];
        else if (k < 2 * NF)   v = h[(long)ssrc[e] * NF + (k - NF)];
        else                   v = ea[(eb + e) * EF + (k - 2 * NF)];
        zT[k][e] = v;
    }

    // register tile: 8 edges x 4 cols per thread. 4 edge-groups x 46 col-groups = 184 threads
    float acc[8][4];
#pragma unroll
    for (int i = 0; i < 8; ++i)
#pragma unroll
        for (int j = 0; j < 4; ++j) acc[i][j] = 0.0f;

    const int eg = tid / 46;
    const int cg = tid - eg * 46;
    const bool act = (tid < 184);
    const int c0 = cg * 4;
    const int e0 = eg * 8;

    for (int kt = 0; kt < NKT; ++kt) {
        __syncthreads();
        for (int i = tid; i < KC * NC; i += EBLOCK) {
            int r = i / NC, c = i - r * NC;
            int kg = kt * KC + r;
            wb[r][c] = (c < NF) ? Wf[kg * NF + c] : Ws[kg * NF + (c - NF)];
        }
        __syncthreads();
        if (act) {
#pragma unroll 5
            for (int r = 0; r < KC; ++r) {
                const int k = kt * KC + r;
                float4 z0 = *(const float4*)(&zT[k][e0]);
                float4 z1 = *(const float4*)(&zT[k][e0 + 4]);
                float4 wf = *(const float4*)(&wb[r][c0]);
                float ze[8] = {z0.x, z0.y, z0.z, z0.w, z1.x, z1.y, z1.z, z1.w};
                float wc[4] = {wf.x, wf.y, wf.z, wf.w};
#pragma unroll
                for (int i = 0; i < 8; ++i)
#pragma unroll
                    for (int j = 0; j < 4; ++j)
                        acc[i][j] = fmaf(ze[i], wc[j], acc[i][j]);
            }
        }
    }

    __syncthreads();
    // stash pre-activation outputs in LDS (reuse zT space: 32*184 = 5888 <= 225*36)
    float* outb = &zT[0][0];
    if (act) {
#pragma unroll
        for (int i = 0; i < 8; ++i) {
            *(float4*)(&outb[(e0 + i) * NC + c0]) =
                make_float4(acc[i][0], acc[i][1], acc[i][2], acc[i][3]);
        }
    }
    __syncthreads();

    // msg = sigmoid(f + bf) * softplus(s + bs); scatter to agg[dst]
    for (int o = tid; o < BE * NF; o += EBLOCK) {
        int e = o / NF, c = o - e * NF;
        float f = outb[e * NC + c] + bf[c];
        float s = outb[e * NC + NF + c] + bs[c];
        float m = sigmoidf_(f) * softplusf_(s);
        atomicAdd(&agg[(long)sdst[e] * NF + c], m);
    }
}

// ---------------- residual + SiLU: a = silu(x + a), elementwise ----------------
__global__ void node_update(const float* __restrict__ x, float* __restrict__ a, int n4)
{
    int i = blockIdx.x * blockDim.x + threadIdx.x;
    int stride = gridDim.x * blockDim.x;
    for (; i < n4; i += stride) {
        float4 xv = ((const float4*)x)[i];
        float4 av = ((float4*)a)[i];
        float4 r;
        r.x = siluf_(xv.x + av.x);
        r.y = siluf_(xv.y + av.y);
        r.z = siluf_(xv.z + av.z);
        r.w = siluf_(xv.w + av.w);
        ((float4*)a)[i] = r;
    }
}

// ---------------- fc1: hout = silu(hin @ W + b), [N,92]@[92,92] ----------------
__global__ __launch_bounds__(256) void fc_node_kernel(
    const float* __restrict__ hin, const float* __restrict__ W,
    const float* __restrict__ b, float* __restrict__ hout)
{
    __shared__ float xt[32][NF];
    __shared__ float wl[NF * NF];
    const int tid = threadIdx.x;
    const int nb = blockIdx.x * 32;

    for (int i = tid; i < NF * NF; i += 256) wl[i] = W[i];
    for (int i = tid; i < 32 * NF; i += 256) {
        int n = i / NF, k = i - n * NF;
        int node = nb + n;
        xt[n][k] = (node < N_NODES) ? hin[(long)node * NF + k] : 0.0f;
    }
    __syncthreads();

    for (int o = tid; o < 32 * NF; o += 256) {
        int n = o / NF, c = o - n * NF;
        int node = nb + n;
        if (node < N_NODES) {
            float a = b[c];
#pragma unroll 4
            for (int k = 0; k < NF; ++k) a = fmaf(xt[n][k], wl[k * NF + c], a);
            hout[(long)node * NF + c] = siluf_(a);
        }
    }
}

// ---------------- mean pool over nodes: pooled[c] = mean(h[:, c]) ----------------
__global__ __launch_bounds__(256) void pool_kernel(const float* __restrict__ h,
                                                   float* __restrict__ pooled)
{
    const int c = blockIdx.x;
    float s = 0.0f;
    for (int n = threadIdx.x; n < N_NODES; n += 256) s += h[(long)n * NF + c];
    for (int off = 32; off; off >>= 1) s += __shfl_down(s, off);
    __shared__ float wsum[4];
    int wid = threadIdx.x >> 6;
    if ((threadIdx.x & 63) == 0) wsum[wid] = s;
    __syncthreads();
    if (threadIdx.x == 0)
        pooled[c] = (wsum[0] + wsum[1] + wsum[2] + wsum[3]) / (float)N_NODES;
}

// ---------------- final MLP: [pooled|glob] (272) -> 1024 -> 512 -> 256 -> 128 -> 64 -> 1 ----------------
__global__ __launch_bounds__(1024) void mlp_kernel(
    const float* __restrict__ pooled, const float* __restrict__ glob,
    const float* __restrict__ W2, const float* __restrict__ b2,
    const float* __restrict__ W3, const float* __restrict__ b3,
    const float* __restrict__ W4, const float* __restrict__ b4,
    const float* __restrict__ W5, const float* __restrict__ b5,
    const float* __restrict__ W6, const float* __restrict__ b6,
    const float* __restrict__ W7, const float* __restrict__ b7,
    float* __restrict__ out)
{
    __shared__ float vin[1024], vout[1024];
    const int t = threadIdx.x;

    if (t < NF) vin[t] = pooled[t];
    else if (t < NF + GF) vin[t] = glob[t - NF];
    __syncthreads();

    { // fc2: 272 -> 1024
        float a = b2[t];
        for (int k = 0; k < NF + GF; ++k) a = fmaf(vin[k], W2[k * 1024 + t], a);
        vout[t] = siluf_(a);
    }
    __syncthreads();
    vin[t] = vout[t];
    __syncthreads();

    if (t < 512) { // fc3: 1024 -> 512
        float a = b3[t];
        for (int k = 0; k < 1024; ++k) a = fmaf(vin[k], W3[k * 512 + t], a);
        vout[t] = siluf_(a);
    }
    __syncthreads();
    if (t < 512) vin[t] = vout[t];
    __syncthreads();

    if (t < 256) { // fc4: 512 -> 256
        float a = b4[t];
        for (int k = 0; k < 512; ++k) a = fmaf(vin[k], W4[k * 256 + t], a);
        vout[t] = siluf_(a);
    }
    __syncthreads();
    if (t < 256) vin[t] = vout[t];
    __syncthreads();

    if (t < 128) { // fc5: 256 -> 128
        float a = b5[t];
        for (int k = 0; k < 256; ++k) a = fmaf(vin[k], W5[k * 128 + t], a);
        vout[t] = siluf_(a);
    }
    __syncthreads();
    if (t < 128) vin[t] = vout[t];
    __syncthreads();

    if (t < 64) { // fc6: 128 -> 64
        float a = b6[t];
        for (int k = 0; k < 128; ++k) a = fmaf(vin[k], W6[k * 64 + t], a);
        vout[t] = siluf_(a);
    }
    __syncthreads();
    if (t < 64) vin[t] = vout[t];
    __syncthreads();

    if (t < 64) { // fc7: 64 -> 1
        float p = vin[t] * W7[t];
        for (int off = 32; off; off >>= 1) p += __shfl_down(p, off);
        if (t == 0) out[0] = p + b7[0];
    }
}

// ---------------- launch ----------------
extern "C" void kernel_launch(void* const* d_in, const int* in_sizes, int n_in,
                              void* d_out, int out_size, void* d_ws, size_t ws_size,
                              hipStream_t stream)
{
    (void)in_sizes; (void)n_in; (void)out_size; (void)ws_size;

    const float* x    = (const float*)d_in[0];
    const int*   ei   = (const int*)d_in[1];
    const float* ea   = (const float*)d_in[2];
    const float* glob = (const float*)d_in[3];
    // d_in[4] = batch (unused; single graph)
    const float* cWf[3] = {(const float*)d_in[5],  (const float*)d_in[9],  (const float*)d_in[13]};
    const float* cbf[3] = {(const float*)d_in[6],  (const float*)d_in[10], (const float*)d_in[14]};
    const float* cWs[3] = {(const float*)d_in[7],  (const float*)d_in[11], (const float*)d_in[15]};
    const float* cbs[3] = {(const float*)d_in[8],  (const float*)d_in[12], (const float*)d_in[16]};
    const float* fc1W = (const float*)d_in[17]; const float* fc1b = (const float*)d_in[18];
    const float* W2 = (const float*)d_in[19];   const float* b2 = (const float*)d_in[20];
    const float* W3 = (const float*)d_in[21];   const float* b3 = (const float*)d_in[22];
    const float* W4 = (const float*)d_in[23];   const float* b4 = (const float*)d_in[24];
    const float* W5 = (const float*)d_in[25];   const float* b5 = (const float*)d_in[26];
    const float* W6 = (const float*)d_in[27];   const float* b6 = (const float*)d_in[28];
    const float* W7 = (const float*)d_in[29];   const float* b7 = (const float*)d_in[30];
    float* out = (float*)d_out;

    const size_t H = (size_t)N_NODES * NF;          // 4.6M floats
    float* b0 = (float*)d_ws;
    float* b1 = b0 + H;
    float* pooled = b1 + H;
    const size_t HB = H * sizeof(float);

    const int nEdgeBlocks = N_EDGES / BE;           // 25000
    const int n4 = (int)(H / 4);
    const int fcBlocks = (N_NODES + 31) / 32;

    // conv1: hcur = x, agg = b0 -> b0 = silu(x + agg)
    hipMemsetAsync(b0, 0, HB, stream);
    edge_kernel<<<nEdgeBlocks, EBLOCK, 0, stream>>>(x, ei, ea, cWf[0], cbf[0], cWs[0], cbs[0], b0);
    node_update<<<2048, 256, 0, stream>>>(x, b0, n4);

    // conv2: hcur = b0, agg = b1 -> b1 = silu(b0 + agg)
    hipMemsetAsync(b1, 0, HB, stream);
    edge_kernel<<<nEdgeBlocks, EBLOCK, 0, stream>>>(b0, ei, ea, cWf[1], cbf[1], cWs[1], cbs[1], b1);
    node_update<<<2048, 256, 0, stream>>>(b0, b1, n4);

    // conv3: hcur = b1, agg = b0 -> b0 = silu(b1 + agg)
    hipMemsetAsync(b0, 0, HB, stream);
    edge_kernel<<<nEdgeBlocks, EBLOCK, 0, stream>>>(b1, ei, ea, cWf[2], cbf[2], cWs[2], cbs[2], b0);
    node_update<<<2048, 256, 0, stream>>>(b1, b0, n4);

    // fc1 twice
    fc_node_kernel<<<fcBlocks, 256, 0, stream>>>(b0, fc1W, fc1b, b1);
    fc_node_kernel<<<fcBlocks, 256, 0, stream>>>(b1, fc1W, fc1b, b0);

    // mean pool + MLP head
    pool_kernel<<<NF, 256, 0, stream>>>(b0, pooled);
    mlp_kernel<<<1, 1024, 0, stream>>>(pooled, glob, W2, b2, W3, b3, W4, b4,
                                       W5, b5, W6, b6, W7, b7, out);
}

// Round 3
// 3060.971 us; speedup vs baseline: 2.5013x; 2.5013x over previous
//
#include <hip/hip_runtime.h>
#include <math.h>

// ---------------- problem constants ----------------
#define N_NODES 50000
#define N_EDGES 800000
#define NF 92           // node features
#define EF 41           // edge features
#define GF 180          // global attr

// MFMA-padded dims
#define NT 12           // N tiles of 16 (cols: [f 0..95 | s 96..191])
#define KS 8            // K steps of 32 (K padded 225 -> 256)
#define BE 64           // edges per block
#define NHP 96          // padded bf16 node row
#define NEP 48          // padded bf16 edge_attr row
#define WC_ELEMS (KS * NT * 64 * 8)   // 49152 bf16 per layer, fragment-major

typedef __attribute__((ext_vector_type(8))) short bf16x8;
typedef __attribute__((ext_vector_type(4))) float f32x4;

__device__ __forceinline__ float sigmoidf_(float x) { return 1.0f / (1.0f + expf(-x)); }
__device__ __forceinline__ float softplusf_(float x) { return fmaxf(x, 0.0f) + log1pf(expf(-fabsf(x))); }
__device__ __forceinline__ float siluf_(float x) { return x * sigmoidf_(x); }

__device__ __forceinline__ unsigned short f2bf(float x) {
    union { float f; unsigned u; } v; v.f = x;
    unsigned r = v.u + 0x7FFF + ((v.u >> 16) & 1);   // RNE
    return (unsigned short)(r >> 16);
}
__device__ __forceinline__ float bf2f(unsigned short h) {
    union { unsigned u; float f; } v; v.u = ((unsigned)h) << 16; return v.f;
}

// ---------------- weight conversion: fp32 -> bf16 hi/lo fragment-major ----------------
// Wc index: (((ks*NT + nt)*64 + lane)*8 + j); element = W[k][n] with
// k = ks*32 + (lane>>4)*8 + j (padded-k), n = nt*16 + (lane&15) (padded-n).
__global__ __launch_bounds__(256) void convert_w(const float* __restrict__ Wf,
                                                 const float* __restrict__ Ws,
                                                 unsigned short* __restrict__ Wh,
                                                 unsigned short* __restrict__ Wl)
{
    int idx = blockIdx.x * 256 + threadIdx.x;
    if (idx >= WC_ELEMS) return;
    int j    = idx & 7;
    int lane = (idx >> 3) & 63;
    int nt   = (idx >> 9) % NT;
    int ks   = idx / (NT * 512);
    int k = ks * 32 + ((lane >> 4) * 8) + j;
    int n = nt * 16 + (lane & 15);
    int r;  // original weight row; -1 = pad
    if      (k < 92)  r = k;          // dst features -> rows 0..91
    else if (k < 96)  r = -1;
    else if (k < 188) r = k - 4;      // src features -> rows 92..183
    else if (k < 192) r = -1;
    else if (k < 233) r = k - 8;      // edge attr    -> rows 184..224
    else              r = -1;
    float val = 0.f;
    if (r >= 0) {
        if (n < 92)                  val = Wf[r * NF + n];
        else if (n >= 96 && n < 188) val = Ws[r * NF + (n - 96)];
    }
    unsigned short hi = f2bf(val);
    Wh[idx] = hi;
    Wl[idx] = f2bf(val - bf2f(hi));
}

// ---------------- fp32 node features -> padded bf16 hi/lo rows ----------------
__global__ __launch_bounds__(256) void convert_x_k(const float* __restrict__ x,
                                                   unsigned short* __restrict__ hh,
                                                   unsigned short* __restrict__ hl)
{
    int i = blockIdx.x * 256 + threadIdx.x;
    if (i >= N_NODES * NHP) return;
    int n = i / NHP, c = i - n * NHP;
    float v = (c < NF) ? x[n * NF + c] : 0.0f;
    unsigned short hi = f2bf(v);
    hh[i] = hi;
    hl[i] = f2bf(v - bf2f(hi));
}

// ---------------- fp32 edge_attr -> padded bf16 hi/lo rows ----------------
__global__ __launch_bounds__(256) void convert_ea_k(const float* __restrict__ ea,
                                                    unsigned short* __restrict__ eh,
                                                    unsigned short* __restrict__ el)
{
    long i = (long)blockIdx.x * 256 + threadIdx.x;
    if (i >= (long)N_EDGES * NEP) return;
    long e = i / NEP; int c = (int)(i - e * NEP);
    float v = (c < EF) ? ea[e * EF + c] : 0.0f;
    unsigned short hi = f2bf(v);
    eh[i] = hi;
    el[i] = f2bf(v - bf2f(hi));
}

// ---------------- fused CGConv edge kernel (bf16x2 split MFMA) ----------------
// 64 edges/block, 6 waves. z_hi and z_lo staged in LDS [64][512B] each, XOR swizzle.
// Wave w computes ntiles (w, w+6) = (f cols, s cols) for all 4 M-tiles via
// zh@Wh + zh@Wl + zl@Wh (fp32-accurate), sigmoid*softplus in-register,
// atomicAdd scatter to agg[dst].
template <bool USE_EB>
__global__ __launch_bounds__(384) void edge_mfma(
    const unsigned short* __restrict__ hh, const unsigned short* __restrict__ hl,
    const int* __restrict__ ei,
    const unsigned short* __restrict__ eh, const unsigned short* __restrict__ el,
    const float* __restrict__ ea,
    const unsigned short* __restrict__ Wh, const unsigned short* __restrict__ Wl,
    const float* __restrict__ bf, const float* __restrict__ bs,
    float* __restrict__ agg)
{
    __shared__ unsigned int zbuf[2 * BE * 128];   // 64KB: [hi 32KB | lo 32KB]

    const int tid = threadIdx.x;
    const long e0 = (long)blockIdx.x * BE;
    char* const zh_base = (char*)zbuf;
    char* const zl_base = (char*)zbuf + 32768;

    // gather: 64 edges x 32 16B-units, hi+lo together; swizzled LDS write
    for (int u = tid; u < BE * 32; u += 384) {
        int e = u >> 5, c16 = u & 31;
        uint4 vh, vl;
        if (c16 < 12) {
            long node = ei[N_EDGES + e0 + e];    // dst
            vh = *(const uint4*)(hh + node * NHP + c16 * 8);
            vl = *(const uint4*)(hl + node * NHP + c16 * 8);
        } else if (c16 < 24) {
            long node = ei[e0 + e];              // src
            vh = *(const uint4*)(hh + node * NHP + (c16 - 12) * 8);
            vl = *(const uint4*)(hl + node * NHP + (c16 - 12) * 8);
        } else if (c16 < 30) {
            if (USE_EB) {
                vh = *(const uint4*)(eh + (e0 + e) * NEP + (long)(c16 - 24) * 8);
                vl = *(const uint4*)(el + (e0 + e) * NEP + (long)(c16 - 24) * 8);
            } else {
                unsigned short th[8], tl[8];
                int base = (c16 - 24) * 8;
#pragma unroll
                for (int j = 0; j < 8; ++j) {
                    int cc = base + j;
                    float v = (cc < EF) ? ea[(e0 + e) * EF + cc] : 0.0f;
                    unsigned short hi = f2bf(v);
                    th[j] = hi;
                    tl[j] = f2bf(v - bf2f(hi));
                }
                vh = *(uint4*)th; vl = *(uint4*)tl;
            }
        } else {
            vh = make_uint4(0u, 0u, 0u, 0u);
            vl = vh;
        }
        int byte = (c16 * 16) ^ ((e & 7) << 4);
        *(uint4*)(zh_base + e * 512 + byte) = vh;
        *(uint4*)(zl_base + e * 512 + byte) = vl;
    }
    __syncthreads();

    const int w    = tid >> 6;      // 0..5 -> ntile pair (w, w+6)
    const int lane = tid & 63;
    const int lr   = lane & 15;
    const int lg   = lane >> 4;

    f32x4 accF[4], accS[4];
#pragma unroll
    for (int m = 0; m < 4; ++m) {
        accF[m] = (f32x4){0.f, 0.f, 0.f, 0.f};
        accS[m] = (f32x4){0.f, 0.f, 0.f, 0.f};
    }

    for (int ks = 0; ks < KS; ++ks) {
        bf16x8 bFh = *(const bf16x8*)(Wh + ((size_t)(ks * NT + w)     * 64 + lane) * 8);
        bf16x8 bSh = *(const bf16x8*)(Wh + ((size_t)(ks * NT + w + 6) * 64 + lane) * 8);
        bf16x8 bFl = *(const bf16x8*)(Wl + ((size_t)(ks * NT + w)     * 64 + lane) * 8);
        bf16x8 bSl = *(const bf16x8*)(Wl + ((size_t)(ks * NT + w + 6) * 64 + lane) * 8);
#pragma unroll
        for (int m = 0; m < 4; ++m) {
            int row  = m * 16 + lr;
            int byte = (ks * 64 + lg * 16) ^ ((row & 7) << 4);
            bf16x8 ah = *(const bf16x8*)(zh_base + row * 512 + byte);
            bf16x8 al = *(const bf16x8*)(zl_base + row * 512 + byte);
            accF[m] = __builtin_amdgcn_mfma_f32_16x16x32_bf16(ah, bFh, accF[m], 0, 0, 0);
            accF[m] = __builtin_amdgcn_mfma_f32_16x16x32_bf16(ah, bFl, accF[m], 0, 0, 0);
            accF[m] = __builtin_amdgcn_mfma_f32_16x16x32_bf16(al, bFh, accF[m], 0, 0, 0);
            accS[m] = __builtin_amdgcn_mfma_f32_16x16x32_bf16(ah, bSh, accS[m], 0, 0, 0);
            accS[m] = __builtin_amdgcn_mfma_f32_16x16x32_bf16(ah, bSl, accS[m], 0, 0, 0);
            accS[m] = __builtin_amdgcn_mfma_f32_16x16x32_bf16(al, bSh, accS[m], 0, 0, 0);
        }
    }

    // epilogue: C layout col=lane&15, row=(lane>>4)*4+reg
    const int c = w * 16 + lr;      // 0..95
    if (c < NF) {
        const float bfv = bf[c];
        const float bsv = bs[c];
#pragma unroll
        for (int m = 0; m < 4; ++m) {
#pragma unroll
            for (int r = 0; r < 4; ++r) {
                int e = m * 16 + lg * 4 + r;
                float fv = accF[m][r] + bfv;
                float sv = accS[m][r] + bsv;
                float msg = sigmoidf_(fv) * softplusf_(sv);
                long dste = ei[N_EDGES + e0 + e];
                atomicAdd(&agg[dste * NF + c], msg);
            }
        }
    }
}

// ---------------- residual + SiLU, fused bf16 hi/lo re-encode ----------------
__global__ __launch_bounds__(256) void node_update_fused(
    const float* __restrict__ xres, float* __restrict__ a,
    unsigned short* __restrict__ hh, unsigned short* __restrict__ hl)
{
    int i = blockIdx.x * 256 + threadIdx.x;
    int stride = gridDim.x * 256;
    for (; i < N_NODES * NF; i += stride) {
        int n = i / NF, cc = i - n * NF;
        float v = siluf_(xres[i] + a[i]);
        a[i] = v;
        unsigned short hi = f2bf(v);
        hh[n * NHP + cc] = hi;
        hl[n * NHP + cc] = f2bf(v - bf2f(hi));
    }
}

// ---------------- fc1: hout = silu(hin @ W + b), [N,92]@[92,92] fp32 ----------------
__global__ __launch_bounds__(256) void fc_node_kernel(
    const float* __restrict__ hin, const float* __restrict__ W,
    const float* __restrict__ b, float* __restrict__ hout)
{
    __shared__ float xt[32][NF];
    __shared__ float wl[NF * NF];
    const int tid = threadIdx.x;
    const int nb = blockIdx.x * 32;

    for (int i = tid; i < NF * NF; i += 256) wl[i] = W[i];
    for (int i = tid; i < 32 * NF; i += 256) {
        int n = i / NF, k = i - n * NF;
        int node = nb + n;
        xt[n][k] = (node < N_NODES) ? hin[(long)node * NF + k] : 0.0f;
    }
    __syncthreads();

    for (int o = tid; o < 32 * NF; o += 256) {
        int n = o / NF, cc = o - n * NF;
        int node = nb + n;
        if (node < N_NODES) {
            float a = b[cc];
#pragma unroll 4
            for (int k = 0; k < NF; ++k) a = fmaf(xt[n][k], wl[k * NF + cc], a);
            hout[(long)node * NF + cc] = siluf_(a);
        }
    }
}

// ---------------- mean pool ----------------
__global__ __launch_bounds__(256) void pool_kernel(const float* __restrict__ h,
                                                   float* __restrict__ pooled)
{
    const int c = blockIdx.x;
    float s = 0.0f;
    for (int n = threadIdx.x; n < N_NODES; n += 256) s += h[(long)n * NF + c];
    for (int off = 32; off; off >>= 1) s += __shfl_down(s, off);
    __shared__ float wsum[4];
    int wid = threadIdx.x >> 6;
    if ((threadIdx.x & 63) == 0) wsum[wid] = s;
    __syncthreads();
    if (threadIdx.x == 0)
        pooled[c] = (wsum[0] + wsum[1] + wsum[2] + wsum[3]) / (float)N_NODES;
}

// ---------------- final MLP head ----------------
__global__ __launch_bounds__(1024) void mlp_kernel(
    const float* __restrict__ pooled, const float* __restrict__ glob,
    const float* __restrict__ W2, const float* __restrict__ b2,
    const float* __restrict__ W3, const float* __restrict__ b3,
    const float* __restrict__ W4, const float* __restrict__ b4,
    const float* __restrict__ W5, const float* __restrict__ b5,
    const float* __restrict__ W6, const float* __restrict__ b6,
    const float* __restrict__ W7, const float* __restrict__ b7,
    float* __restrict__ out)
{
    __shared__ float vin[1024], vout[1024];
    const int t = threadIdx.x;

    if (t < NF) vin[t] = pooled[t];
    else if (t < NF + GF) vin[t] = glob[t - NF];
    __syncthreads();

    { // fc2: 272 -> 1024
        float a = b2[t];
        for (int k = 0; k < NF + GF; ++k) a = fmaf(vin[k], W2[k * 1024 + t], a);
        vout[t] = siluf_(a);
    }
    __syncthreads();
    vin[t] = vout[t];
    __syncthreads();

    if (t < 512) { // fc3
        float a = b3[t];
        for (int k = 0; k < 1024; ++k) a = fmaf(vin[k], W3[k * 512 + t], a);
        vout[t] = siluf_(a);
    }
    __syncthreads();
    if (t < 512) vin[t] = vout[t];
    __syncthreads();

    if (t < 256) { // fc4
        float a = b4[t];
        for (int k = 0; k < 512; ++k) a = fmaf(vin[k], W4[k * 256 + t], a);
        vout[t] = siluf_(a);
    }
    __syncthreads();
    if (t < 256) vin[t] = vout[t];
    __syncthreads();

    if (t < 128) { // fc5
        float a = b5[t];
        for (int k = 0; k < 256; ++k) a = fmaf(vin[k], W5[k * 128 + t], a);
        vout[t] = siluf_(a);
    }
    __syncthreads();
    if (t < 128) vin[t] = vout[t];
    __syncthreads();

    if (t < 64) { // fc6
        float a = b6[t];
        for (int k = 0; k < 128; ++k) a = fmaf(vin[k], W6[k * 64 + t], a);
        vout[t] = siluf_(a);
    }
    __syncthreads();
    if (t < 64) vin[t] = vout[t];
    __syncthreads();

    if (t < 64) { // fc7: 64 -> 1
        float p = vin[t] * W7[t];
        for (int off = 32; off; off >>= 1) p += __shfl_down(p, off);
        if (t == 0) out[0] = p + b7[0];
    }
}

// ---------------- launch ----------------
extern "C" void kernel_launch(void* const* d_in, const int* in_sizes, int n_in,
                              void* d_out, int out_size, void* d_ws, size_t ws_size,
                              hipStream_t stream)
{
    (void)in_sizes; (void)n_in; (void)out_size;

    const float* x    = (const float*)d_in[0];
    const int*   ei   = (const int*)d_in[1];
    const float* ea   = (const float*)d_in[2];
    const float* glob = (const float*)d_in[3];
    const float* cWf[3] = {(const float*)d_in[5],  (const float*)d_in[9],  (const float*)d_in[13]};
    const float* cbf[3] = {(const float*)d_in[6],  (const float*)d_in[10], (const float*)d_in[14]};
    const float* cWs[3] = {(const float*)d_in[7],  (const float*)d_in[11], (const float*)d_in[15]};
    const float* cbs[3] = {(const float*)d_in[8],  (const float*)d_in[12], (const float*)d_in[16]};
    const float* fc1W = (const float*)d_in[17]; const float* fc1b = (const float*)d_in[18];
    const float* W2 = (const float*)d_in[19];   const float* b2 = (const float*)d_in[20];
    const float* W3 = (const float*)d_in[21];   const float* b3 = (const float*)d_in[22];
    const float* W4 = (const float*)d_in[23];   const float* b4 = (const float*)d_in[24];
    const float* W5 = (const float*)d_in[25];   const float* b5 = (const float*)d_in[26];
    const float* W6 = (const float*)d_in[27];   const float* b6 = (const float*)d_in[28];
    const float* W7 = (const float*)d_in[29];   const float* b7 = (const float*)d_in[30];
    float* out = (float*)d_out;

    const size_t H = (size_t)N_NODES * NF;
    float* b0 = (float*)d_ws;
    float* b1 = b0 + H;
    float* pooled = b1 + H;                                  // 128 floats reserved
    unsigned short* hh = (unsigned short*)(pooled + 128);    // N*96 bf16 hi
    unsigned short* hl = hh + (size_t)N_NODES * NHP;         // N*96 bf16 lo
    unsigned short* Wch = hl + (size_t)N_NODES * NHP;        // 3*49152 hi
    unsigned short* Wcl = Wch + 3 * (size_t)WC_ELEMS;        // 3*49152 lo
    unsigned short* ebh = Wcl + 3 * (size_t)WC_ELEMS;        // E*48 hi
    unsigned short* ebl = ebh + (size_t)N_EDGES * NEP;       // E*48 lo
    const size_t need_full = (size_t)((char*)(ebl + (size_t)N_EDGES * NEP) - (char*)d_ws);
    const bool use_eb = ws_size >= need_full;

    const size_t HB = H * sizeof(float);
    const int nEdgeBlocks = N_EDGES / BE;                    // 12500
    const int fcBlocks = (N_NODES + 31) / 32;

    // one-time conversions
    for (int l = 0; l < 3; ++l)
        convert_w<<<(WC_ELEMS + 255) / 256, 256, 0, stream>>>(
            cWf[l], cWs[l], Wch + (size_t)l * WC_ELEMS, Wcl + (size_t)l * WC_ELEMS);
    convert_x_k<<<(N_NODES * NHP + 255) / 256, 256, 0, stream>>>(x, hh, hl);
    if (use_eb)
        convert_ea_k<<<(int)(((long)N_EDGES * NEP + 255) / 256), 256, 0, stream>>>(ea, ebh, ebl);

    for (int l = 0; l < 3; ++l) {
        const float* xres = (l == 0) ? x : ((l == 1) ? b0 : b1);
        float* aggb = (l == 1) ? b1 : b0;    // l0->b0, l1->b1, l2->b0
        hipMemsetAsync(aggb, 0, HB, stream);
        if (use_eb)
            edge_mfma<true><<<nEdgeBlocks, 384, 0, stream>>>(hh, hl, ei, ebh, ebl, ea,
                Wch + (size_t)l * WC_ELEMS, Wcl + (size_t)l * WC_ELEMS, cbf[l], cbs[l], aggb);
        else
            edge_mfma<false><<<nEdgeBlocks, 384, 0, stream>>>(hh, hl, ei, ebh, ebl, ea,
                Wch + (size_t)l * WC_ELEMS, Wcl + (size_t)l * WC_ELEMS, cbf[l], cbs[l], aggb);
        node_update_fused<<<2048, 256, 0, stream>>>(xres, aggb, hh, hl);
    }

    // fc1 twice: b0 -> b1 -> b0
    fc_node_kernel<<<fcBlocks, 256, 0, stream>>>(b0, fc1W, fc1b, b1);
    fc_node_kernel<<<fcBlocks, 256, 0, stream>>>(b1, fc1W, fc1b, b0);

    pool_kernel<<<NF, 256, 0, stream>>>(b0, pooled);
    mlp_kernel<<<1, 1024, 0, stream>>>(pooled, glob, W2, b2, W3, b3, W4, b4,
                                       W5, b5, W6, b6, W7, b7, out);
}

// Round 4
// 1866.363 us; speedup vs baseline: 4.1022x; 1.6401x over previous
//
#include <hip/hip_runtime.h>
#include <math.h>

// ---------------- problem constants ----------------
#define N_NODES 50000
#define N_EDGES 800000
#define NF 92           // node features
#define EF 41           // edge features
#define GF 180          // global attr
#define NHP 96          // padded bf16 node row

// node-GEMM: [50k,96] @ [96,384] (cols = Pf|Qf|Ps|Qs), KS_N=3, NT_N=24
#define WCN_ELEMS (3 * 24 * 64 * 8)   // 36864 per layer
// edge-GEMM: [800k,64] @ [64,192] (ea part only), KS_E=2, NT_E=12
#define WCE_ELEMS (2 * 12 * 64 * 8)   // 12288 per layer

typedef __attribute__((ext_vector_type(8))) short bf16x8;
typedef __attribute__((ext_vector_type(4))) float f32x4;

__device__ __forceinline__ float sigmoidf_(float x) { return 1.0f / (1.0f + expf(-x)); }
__device__ __forceinline__ float softplusf_(float x) { return fmaxf(x, 0.0f) + log1pf(expf(-fabsf(x))); }
__device__ __forceinline__ float siluf_(float x) { return x * sigmoidf_(x); }

__device__ __forceinline__ unsigned short f2bf(float x) {
    union { float f; unsigned u; } v; v.f = x;
    unsigned r = v.u + 0x7FFF + ((v.u >> 16) & 1);   // RNE
    return (unsigned short)(r >> 16);
}
__device__ __forceinline__ float bf2f(unsigned short h) {
    union { unsigned u; float f; } v; v.u = ((unsigned)h) << 16; return v.f;
}

// ---------------- node-weight conversion: fragment-major hi/lo ----------------
// k = ks*32 + (lane>>4)*8 + j in [0,96); n = nt*16 + (lane&15) in [0,384)
// table t = n/96 (0:Wf-dst 1:Wf-src 2:Ws-dst 3:Ws-src), col = n%96
__global__ __launch_bounds__(256) void convert_w_node(const float* __restrict__ Wf,
                                                      const float* __restrict__ Ws,
                                                      unsigned short* __restrict__ Wh,
                                                      unsigned short* __restrict__ Wl)
{
    int idx = blockIdx.x * 256 + threadIdx.x;
    if (idx >= WCN_ELEMS) return;
    int j    = idx & 7;
    int lane = (idx >> 3) & 63;
    int nt   = (idx >> 9) % 24;
    int ks   = idx / (24 * 512);
    int k = ks * 32 + ((lane >> 4) * 8) + j;
    int n = nt * 16 + (lane & 15);
    int t = n / 96, col = n % 96;
    float val = 0.f;
    if (k < 92 && col < 92) {
        const float* W = (t < 2) ? Wf : Ws;
        int rowoff = (t & 1) ? 92 : 0;
        val = W[(rowoff + k) * NF + col];
    }
    unsigned short hi = f2bf(val);
    Wh[idx] = hi;
    Wl[idx] = f2bf(val - bf2f(hi));
}

// ---------------- edge-weight conversion (W rows 184..224) ----------------
// k = ks*32 + (lane>>4)*8 + j in [0,64); n = nt*16 + (lane&15) in [0,192)
__global__ __launch_bounds__(256) void convert_w_edge(const float* __restrict__ Wf,
                                                      const float* __restrict__ Ws,
                                                      unsigned short* __restrict__ Wh,
                                                      unsigned short* __restrict__ Wl)
{
    int idx = blockIdx.x * 256 + threadIdx.x;
    if (idx >= WCE_ELEMS) return;
    int j    = idx & 7;
    int lane = (idx >> 3) & 63;
    int nt   = (idx >> 9) % 12;
    int ks   = idx / (12 * 512);
    int k = ks * 32 + ((lane >> 4) * 8) + j;
    int n = nt * 16 + (lane & 15);
    float val = 0.f;
    if (k < EF) {
        if (n < 92)                  val = Wf[(184 + k) * NF + n];
        else if (n >= 96 && n < 188) val = Ws[(184 + k) * NF + (n - 96)];
    }
    unsigned short hi = f2bf(val);
    Wh[idx] = hi;
    Wl[idx] = f2bf(val - bf2f(hi));
}

// ---------------- fp32 node features -> padded bf16 hi/lo rows ----------------
__global__ __launch_bounds__(256) void convert_x_k(const float* __restrict__ x,
                                                   unsigned short* __restrict__ hh,
                                                   unsigned short* __restrict__ hl)
{
    int i = blockIdx.x * 256 + threadIdx.x;
    if (i >= N_NODES * NHP) return;
    int n = i / NHP, c = i - n * NHP;
    float v = (c < NF) ? x[n * NF + c] : 0.0f;
    unsigned short hi = f2bf(v);
    hh[i] = hi;
    hl[i] = f2bf(v - bf2f(hi));
}

// ---------------- node GEMM: P[t][node*96+col] = (h @ Wnode)[node, n] ----------------
// 64 nodes/block, 6 waves; split-bf16 (fp32-accurate). LDS 32KB.
__global__ __launch_bounds__(384) void node_mfma(
    const unsigned short* __restrict__ hh, const unsigned short* __restrict__ hl,
    const unsigned short* __restrict__ Wh, const unsigned short* __restrict__ Wl,
    float* __restrict__ P)
{
    __shared__ char zz[2 * 64 * 256];     // hi | lo, 256B rows
    const int tid = threadIdx.x;
    const int n0 = blockIdx.x * 64;
    char* const zh = zz;
    char* const zl = zz + 64 * 256;

    for (int u = tid; u < 64 * 16; u += 384) {
        int e = u >> 4, c16 = u & 15;
        uint4 vh = make_uint4(0, 0, 0, 0), vl = vh;
        int node = n0 + e;
        if (c16 < 12 && node < N_NODES) {
            vh = *(const uint4*)(hh + (size_t)node * NHP + c16 * 8);
            vl = *(const uint4*)(hl + (size_t)node * NHP + c16 * 8);
        }
        int byte = (c16 * 16) ^ ((e & 7) << 4);
        *(uint4*)(zh + e * 256 + byte) = vh;
        *(uint4*)(zl + e * 256 + byte) = vl;
    }
    __syncthreads();

    const int w = tid >> 6, lane = tid & 63, lr = lane & 15, lg = lane >> 4;

    for (int ntx = 0; ntx < 4; ++ntx) {
        const int nt = w + 6 * ntx;
        f32x4 acc[4];
#pragma unroll
        for (int m = 0; m < 4; ++m) acc[m] = (f32x4){0.f, 0.f, 0.f, 0.f};

#pragma unroll
        for (int ks = 0; ks < 3; ++ks) {
            bf16x8 bh = *(const bf16x8*)(Wh + ((size_t)(ks * 24 + nt) * 64 + lane) * 8);
            bf16x8 bl = *(const bf16x8*)(Wl + ((size_t)(ks * 24 + nt) * 64 + lane) * 8);
#pragma unroll
            for (int m = 0; m < 4; ++m) {
                int row  = m * 16 + lr;
                int byte = (ks * 64 + lg * 16) ^ ((row & 7) << 4);
                bf16x8 ah = *(const bf16x8*)(zh + row * 256 + byte);
                bf16x8 al = *(const bf16x8*)(zl + row * 256 + byte);
                acc[m] = __builtin_amdgcn_mfma_f32_16x16x32_bf16(ah, bh, acc[m], 0, 0, 0);
                acc[m] = __builtin_amdgcn_mfma_f32_16x16x32_bf16(ah, bl, acc[m], 0, 0, 0);
                acc[m] = __builtin_amdgcn_mfma_f32_16x16x32_bf16(al, bh, acc[m], 0, 0, 0);
            }
        }

        const int t = nt / 6, col = (nt % 6) * 16 + lr;
        float* p = P + (size_t)t * N_NODES * 96;
        if (col < NF) {
#pragma unroll
            for (int m = 0; m < 4; ++m)
#pragma unroll
                for (int r = 0; r < 4; ++r) {
                    int node = n0 + m * 16 + lg * 4 + r;
                    if (node < N_NODES) p[(size_t)node * 96 + col] = acc[m][r];
                }
        }
    }
}

// ---------------- edge kernel: R = ea@We (MFMA) + P/Q gather + act + atomic ----------------
// 64 edges/block, 6 waves, LDS ~17KB -> high occupancy.
__global__ __launch_bounds__(384) void edge_mfma2(
    const int* __restrict__ ei, const float* __restrict__ ea,
    const unsigned short* __restrict__ Wh, const unsigned short* __restrict__ Wl,
    const float* __restrict__ P,
    const float* __restrict__ bf, const float* __restrict__ bs,
    float* __restrict__ agg)
{
    __shared__ char zz[2 * 64 * 128];     // ea hi | lo, 128B rows
    __shared__ int sdst[64], ssrc[64];

    const int tid = threadIdx.x;
    const long e0 = (long)blockIdx.x * 64;
    char* const zh = zz;
    char* const zl = zz + 64 * 128;

    if (tid < 64) {
        ssrc[tid] = ei[e0 + tid];
        sdst[tid] = ei[N_EDGES + e0 + tid];
    }

    // stage ea (on-the-fly fp32 -> bf16 hi/lo), swizzled
    for (int u = tid; u < 64 * 8; u += 384) {
        int e = u >> 3, j = u & 7;
        const float* ear = ea + (e0 + e) * EF;
        unsigned short th[8], tl[8];
#pragma unroll
        for (int jj = 0; jj < 8; ++jj) {
            int cc = j * 8 + jj;
            float v = (cc < EF) ? ear[cc] : 0.0f;
            unsigned short hi = f2bf(v);
            th[jj] = hi;
            tl[jj] = f2bf(v - bf2f(hi));
        }
        int byte = (j * 16) ^ ((e & 7) << 4);
        *(uint4*)(zh + e * 128 + byte) = *(uint4*)th;
        *(uint4*)(zl + e * 128 + byte) = *(uint4*)tl;
    }
    __syncthreads();

    const int w = tid >> 6, lane = tid & 63, lr = lane & 15, lg = lane >> 4;

    f32x4 accF[4], accS[4];
#pragma unroll
    for (int m = 0; m < 4; ++m) {
        accF[m] = (f32x4){0.f, 0.f, 0.f, 0.f};
        accS[m] = (f32x4){0.f, 0.f, 0.f, 0.f};
    }

#pragma unroll
    for (int ks = 0; ks < 2; ++ks) {
        bf16x8 bFh = *(const bf16x8*)(Wh + ((size_t)(ks * 12 + w)     * 64 + lane) * 8);
        bf16x8 bFl = *(const bf16x8*)(Wl + ((size_t)(ks * 12 + w)     * 64 + lane) * 8);
        bf16x8 bSh = *(const bf16x8*)(Wh + ((size_t)(ks * 12 + w + 6) * 64 + lane) * 8);
        bf16x8 bSl = *(const bf16x8*)(Wl + ((size_t)(ks * 12 + w + 6) * 64 + lane) * 8);
#pragma unroll
        for (int m = 0; m < 4; ++m) {
            int row  = m * 16 + lr;
            int byte = (ks * 64 + lg * 16) ^ ((row & 7) << 4);
            bf16x8 ah = *(const bf16x8*)(zh + row * 128 + byte);
            bf16x8 al = *(const bf16x8*)(zl + row * 128 + byte);
            accF[m] = __builtin_amdgcn_mfma_f32_16x16x32_bf16(ah, bFh, accF[m], 0, 0, 0);
            accF[m] = __builtin_amdgcn_mfma_f32_16x16x32_bf16(ah, bFl, accF[m], 0, 0, 0);
            accF[m] = __builtin_amdgcn_mfma_f32_16x16x32_bf16(al, bFh, accF[m], 0, 0, 0);
            accS[m] = __builtin_amdgcn_mfma_f32_16x16x32_bf16(ah, bSh, accS[m], 0, 0, 0);
            accS[m] = __builtin_amdgcn_mfma_f32_16x16x32_bf16(ah, bSl, accS[m], 0, 0, 0);
            accS[m] = __builtin_amdgcn_mfma_f32_16x16x32_bf16(al, bSh, accS[m], 0, 0, 0);
        }
    }

    // epilogue: f/s = R + P[dst] + Q[src] + bias; msg; atomic scatter
    const int c = w * 16 + lr;
    if (c < NF) {
        const float bfv = bf[c];
        const float bsv = bs[c];
        const float* Pf = P;
        const float* Qf = P + (size_t)N_NODES * 96;
        const float* Ps = P + (size_t)2 * N_NODES * 96;
        const float* Qs = P + (size_t)3 * N_NODES * 96;
#pragma unroll
        for (int m = 0; m < 4; ++m) {
#pragma unroll
            for (int r = 0; r < 4; ++r) {
                int e = m * 16 + lg * 4 + r;
                int dst = sdst[e], src = ssrc[e];
                float f = accF[m][r] + Pf[(size_t)dst * 96 + c] + Qf[(size_t)src * 96 + c] + bfv;
                float s = accS[m][r] + Ps[(size_t)dst * 96 + c] + Qs[(size_t)src * 96 + c] + bsv;
                float msg = sigmoidf_(f) * softplusf_(s);
                atomicAdd(&agg[(size_t)dst * NF + c], msg);
            }
        }
    }
}

// ---------------- residual + SiLU, fused bf16 hi/lo re-encode ----------------
__global__ __launch_bounds__(256) void node_update_fused(
    const float* __restrict__ xres, float* __restrict__ a,
    unsigned short* __restrict__ hh, unsigned short* __restrict__ hl)
{
    int i = blockIdx.x * 256 + threadIdx.x;
    int stride = gridDim.x * 256;
    for (; i < N_NODES * NF; i += stride) {
        int n = i / NF, cc = i - n * NF;
        float v = siluf_(xres[i] + a[i]);
        a[i] = v;
        unsigned short hi = f2bf(v);
        hh[n * NHP + cc] = hi;
        hl[n * NHP + cc] = f2bf(v - bf2f(hi));
    }
}

// ---------------- fc1: hout = silu(hin @ W + b), [N,92]@[92,92] fp32 ----------------
__global__ __launch_bounds__(256) void fc_node_kernel(
    const float* __restrict__ hin, const float* __restrict__ W,
    const float* __restrict__ b, float* __restrict__ hout)
{
    __shared__ float xt[32][NF];
    __shared__ float wl[NF * NF];
    const int tid = threadIdx.x;
    const int nb = blockIdx.x * 32;

    for (int i = tid; i < NF * NF; i += 256) wl[i] = W[i];
    for (int i = tid; i < 32 * NF; i += 256) {
        int n = i / NF, k = i - n * NF;
        int node = nb + n;
        xt[n][k] = (node < N_NODES) ? hin[(long)node * NF + k] : 0.0f;
    }
    __syncthreads();

    for (int o = tid; o < 32 * NF; o += 256) {
        int n = o / NF, cc = o - n * NF;
        int node = nb + n;
        if (node < N_NODES) {
            float a = b[cc];
#pragma unroll 4
            for (int k = 0; k < NF; ++k) a = fmaf(xt[n][k], wl[k * NF + cc], a);
            hout[(long)node * NF + cc] = siluf_(a);
        }
    }
}

// ---------------- mean pool ----------------
__global__ __launch_bounds__(256) void pool_kernel(const float* __restrict__ h,
                                                   float* __restrict__ pooled)
{
    const int c = blockIdx.x;
    float s = 0.0f;
    for (int n = threadIdx.x; n < N_NODES; n += 256) s += h[(long)n * NF + c];
    for (int off = 32; off; off >>= 1) s += __shfl_down(s, off);
    __shared__ float wsum[4];
    int wid = threadIdx.x >> 6;
    if ((threadIdx.x & 63) == 0) wsum[wid] = s;
    __syncthreads();
    if (threadIdx.x == 0)
        pooled[c] = (wsum[0] + wsum[1] + wsum[2] + wsum[3]) / (float)N_NODES;
}

// ---------------- final MLP head ----------------
__global__ __launch_bounds__(1024) void mlp_kernel(
    const float* __restrict__ pooled, const float* __restrict__ glob,
    const float* __restrict__ W2, const float* __restrict__ b2,
    const float* __restrict__ W3, const float* __restrict__ b3,
    const float* __restrict__ W4, const float* __restrict__ b4,
    const float* __restrict__ W5, const float* __restrict__ b5,
    const float* __restrict__ W6, const float* __restrict__ b6,
    const float* __restrict__ W7, const float* __restrict__ b7,
    float* __restrict__ out)
{
    __shared__ float vin[1024], vout[1024];
    const int t = threadIdx.x;

    if (t < NF) vin[t] = pooled[t];
    else if (t < NF + GF) vin[t] = glob[t - NF];
    __syncthreads();

    { // fc2: 272 -> 1024
        float a = b2[t];
        for (int k = 0; k < NF + GF; ++k) a = fmaf(vin[k], W2[k * 1024 + t], a);
        vout[t] = siluf_(a);
    }
    __syncthreads();
    vin[t] = vout[t];
    __syncthreads();

    if (t < 512) { // fc3
        float a = b3[t];
        for (int k = 0; k < 1024; ++k) a = fmaf(vin[k], W3[k * 512 + t], a);
        vout[t] = siluf_(a);
    }
    __syncthreads();
    if (t < 512) vin[t] = vout[t];
    __syncthreads();

    if (t < 256) { // fc4
        float a = b4[t];
        for (int k = 0; k < 512; ++k) a = fmaf(vin[k], W4[k * 256 + t], a);
        vout[t] = siluf_(a);
    }
    __syncthreads();
    if (t < 256) vin[t] = vout[t];
    __syncthreads();

    if (t < 128) { // fc5
        float a = b5[t];
        for (int k = 0; k < 256; ++k) a = fmaf(vin[k], W5[k * 128 + t], a);
        vout[t] = siluf_(a);
    }
    __syncthreads();
    if (t < 128) vin[t] = vout[t];
    __syncthreads();

    if (t < 64) { // fc6
        float a = b6[t];
        for (int k = 0; k < 128; ++k) a = fmaf(vin[k], W6[k * 64 + t], a);
        vout[t] = siluf_(a);
    }
    __syncthreads();
    if (t < 64) vin[t] = vout[t];
    __syncthreads();

    if (t < 64) { // fc7: 64 -> 1
        float p = vin[t] * W7[t];
        for (int off = 32; off; off >>= 1) p += __shfl_down(p, off);
        if (t == 0) out[0] = p + b7[0];
    }
}

// ---------------- launch ----------------
extern "C" void kernel_launch(void* const* d_in, const int* in_sizes, int n_in,
                              void* d_out, int out_size, void* d_ws, size_t ws_size,
                              hipStream_t stream)
{
    (void)in_sizes; (void)n_in; (void)out_size; (void)ws_size;

    const float* x    = (const float*)d_in[0];
    const int*   ei   = (const int*)d_in[1];
    const float* ea   = (const float*)d_in[2];
    const float* glob = (const float*)d_in[3];
    const float* cWf[3] = {(const float*)d_in[5],  (const float*)d_in[9],  (const float*)d_in[13]};
    const float* cbf[3] = {(const float*)d_in[6],  (const float*)d_in[10], (const float*)d_in[14]};
    const float* cWs[3] = {(const float*)d_in[7],  (const float*)d_in[11], (const float*)d_in[15]};
    const float* cbs[3] = {(const float*)d_in[8],  (const float*)d_in[12], (const float*)d_in[16]};
    const float* fc1W = (const float*)d_in[17]; const float* fc1b = (const float*)d_in[18];
    const float* W2 = (const float*)d_in[19];   const float* b2 = (const float*)d_in[20];
    const float* W3 = (const float*)d_in[21];   const float* b3 = (const float*)d_in[22];
    const float* W4 = (const float*)d_in[23];   const float* b4 = (const float*)d_in[24];
    const float* W5 = (const float*)d_in[25];   const float* b5 = (const float*)d_in[26];
    const float* W6 = (const float*)d_in[27];   const float* b6 = (const float*)d_in[28];
    const float* W7 = (const float*)d_in[29];   const float* b7 = (const float*)d_in[30];
    float* out = (float*)d_out;

    const size_t H = (size_t)N_NODES * NF;
    float* b0 = (float*)d_ws;                                // [N,92] fp32
    float* b1 = b0 + H;
    float* pooled = b1 + H;                                  // 128 floats
    unsigned short* hh   = (unsigned short*)(pooled + 128);  // N*96 bf16 hi
    unsigned short* hl   = hh + (size_t)N_NODES * NHP;       // N*96 bf16 lo
    unsigned short* WcNh = hl + (size_t)N_NODES * NHP;       // 3*36864
    unsigned short* WcNl = WcNh + 3 * (size_t)WCN_ELEMS;
    unsigned short* WcEh = WcNl + 3 * (size_t)WCN_ELEMS;     // 3*12288
    unsigned short* WcEl = WcEh + 3 * (size_t)WCE_ELEMS;
    float* P = (float*)(WcEl + 3 * (size_t)WCE_ELEMS);       // 4 * N * 96 fp32

    const size_t HB = H * sizeof(float);
    const int nEdgeBlocks = N_EDGES / 64;                    // 12500
    const int nNodeBlocks = (N_NODES + 63) / 64;             // 782
    const int fcBlocks = (N_NODES + 31) / 32;

    // one-time conversions
    for (int l = 0; l < 3; ++l) {
        convert_w_node<<<(WCN_ELEMS + 255) / 256, 256, 0, stream>>>(
            cWf[l], cWs[l], WcNh + (size_t)l * WCN_ELEMS, WcNl + (size_t)l * WCN_ELEMS);
        convert_w_edge<<<(WCE_ELEMS + 255) / 256, 256, 0, stream>>>(
            cWf[l], cWs[l], WcEh + (size_t)l * WCE_ELEMS, WcEl + (size_t)l * WCE_ELEMS);
    }
    convert_x_k<<<(N_NODES * NHP + 255) / 256, 256, 0, stream>>>(x, hh, hl);

    for (int l = 0; l < 3; ++l) {
        const float* xres = (l == 0) ? x : ((l == 1) ? b0 : b1);
        float* aggb = (l == 1) ? b1 : b0;    // l0->b0, l1->b1, l2->b0
        node_mfma<<<nNodeBlocks, 384, 0, stream>>>(hh, hl,
            WcNh + (size_t)l * WCN_ELEMS, WcNl + (size_t)l * WCN_ELEMS, P);
        hipMemsetAsync(aggb, 0, HB, stream);
        edge_mfma2<<<nEdgeBlocks, 384, 0, stream>>>(ei, ea,
            WcEh + (size_t)l * WCE_ELEMS, WcEl + (size_t)l * WCE_ELEMS,
            P, cbf[l], cbs[l], aggb);
        node_update_fused<<<2048, 256, 0, stream>>>(xres, aggb, hh, hl);
    }

    // fc1 twice: b0 -> b1 -> b0
    fc_node_kernel<<<fcBlocks, 256, 0, stream>>>(b0, fc1W, fc1b, b1);
    fc_node_kernel<<<fcBlocks, 256, 0, stream>>>(b1, fc1W, fc1b, b0);

    pool_kernel<<<NF, 256, 0, stream>>>(b0, pooled);
    mlp_kernel<<<1, 1024, 0, stream>>>(pooled, glob, W2, b2, W3, b3, W4, b4,
                                       W5, b5, W6, b6, W7, b7, out);
}